// Round 3
// baseline (559.379 us; speedup 1.0000x reference)
//
#include <hip/hip_runtime.h>

// Problem dims (fixed by harness)
#define NN 512
#define LL 1024
#define SS 3
#define DD 128
#define KK 4
#define HH 32
#define GG 64

// DPP ctrl encodings (gfx9/CDNA): cross-lane moves on the VALU pipe.
#define DPP_XOR1 0xB1   // quad_perm [1,0,3,2]  == lane ^ 1
#define DPP_XOR2 0x4E   // quad_perm [2,3,0,1]  == lane ^ 2
#define DPP_ROR4 0x124  // row_ror:4  (preserves k = r&3 class)
#define DPP_ROR8 0x128  // row_ror:8
#define SWZ16 0x401F    // ds_swizzle BitMode xor-16 within 32-lane group

template <int CTRL>
__device__ __forceinline__ float dppf(float x) {
    return __int_as_float(__builtin_amdgcn_update_dpp(
        0, __float_as_int(x), CTRL, 0xF, 0xF, true));
}
__device__ __forceinline__ float swz16f(float x) {
    return __int_as_float(__builtin_amdgcn_ds_swizzle(__float_as_int(x), SWZ16));
}

// tanh-form GELU: max |err| vs exact erf-GELU ~3e-4 -- far under threshold.
__device__ __forceinline__ float fast_gelu(float x) {
    const float c0 = 0.7978845608028654f;
    const float c1 = 0.7978845608028654f * 0.044715f;
    float u = x * x;
    float y = x * fmaf(c1, u, c0);
    float e = __expf(2.0f * y);
    float r = __builtin_amdgcn_rcpf(e + 1.0f);
    float t = fmaf(-2.0f, r, 1.0f);
    return 0.5f * x * (1.0f + t);
}

// Factorized-softmax fused kernel (see R2) + EXPLICIT software pipeline:
// body i issues cust loads, then edge loads for i+1 into the alternate
// named buffer (ping-pong, hand-unrolled x2 so all indices are static).
// Edge regs consumed in body i are the OLDEST outstanding loads, so the
// compiler's vmcnt leaves the 8 newer loads in flight under the whole
// compute phase. Single tree-accumulator + LDS aliasing free the VGPRs
// that R2's compiler heuristic (64 VGPR) starved the pipeline of.
#define BODY(I, EVC, EVN, PF)                                                   \
  {                                                                             \
    const int e0 = base_el + (I) * 64;                                          \
    /* cust loads for this body (consumed at the bottom) */                     \
    float4 v0 = cp[(base_el + 16 * (I)      ) * 32 + r];                        \
    float4 v1 = cp[(base_el + 16 * (I) + 256) * 32 + r];                        \
    float4 v2 = cp[(base_el + 16 * (I) + 512) * 32 + r];                        \
    float4 v3 = cp[(base_el + 16 * (I) + 768) * 32 + r];                        \
    if (PF) {                                                                   \
      _Pragma("unroll")                                                         \
      for (int u = 0; u < 4; ++u)                                               \
        EVN[u] = *(const float4*)(ed_base + (size_t)(e0 + 64 + u * 16) * DD + r * 4); \
    }                                                                           \
    float s0[4], s1[4], s2[4];                                                  \
    _Pragma("unroll")                                                           \
    for (int u = 0; u < 4; ++u) {                                               \
      const int el = e0 + u * 16;                                               \
      s0[u] = sc_lds[el * 3 + 0];                                               \
      s1[u] = sc_lds[el * 3 + 1];                                               \
      s2[u] = sc_lds[el * 3 + 2];                                               \
    }                                                                           \
    float p0[4], p1[4], p2[4], p3[4];                                           \
    _Pragma("unroll")                                                           \
    for (int u = 0; u < 4; ++u) {                                               \
      p0[u] = fmaf(EVC[u].x, wqa.x, fmaf(EVC[u].y, wqb.x, fmaf(EVC[u].z, wqc.x, EVC[u].w * wqd.x))); \
      p1[u] = fmaf(EVC[u].x, wqa.y, fmaf(EVC[u].y, wqb.y, fmaf(EVC[u].z, wqc.y, EVC[u].w * wqd.y))); \
      p2[u] = fmaf(EVC[u].x, wqa.z, fmaf(EVC[u].y, wqb.z, fmaf(EVC[u].z, wqc.z, EVC[u].w * wqd.z))); \
      p3[u] = fmaf(EVC[u].x, wqa.w, fmaf(EVC[u].y, wqb.w, fmaf(EVC[u].z, wqc.w, EVC[u].w * wqd.w))); \
    }                                                                           \
    float P0[4], P2[4];                                                         \
    _Pragma("unroll")                                                           \
    for (int u = 0; u < 4; ++u) {                                               \
      float g0 = kb0 ? p0[u] : p1[u];                                           \
      float g2 = kb0 ? p2[u] : p3[u];                                           \
      float k0 = kb0 ? p1[u] : p0[u];                                           \
      float k2 = kb0 ? p3[u] : p2[u];                                           \
      P0[u] = k0 + dppf<DPP_XOR1>(g0);                                          \
      P2[u] = k2 + dppf<DPP_XOR1>(g2);                                          \
    }                                                                           \
    float q[4];                                                                 \
    _Pragma("unroll")                                                           \
    for (int u = 0; u < 4; ++u) {                                               \
      float gv = kb1 ? P0[u] : P2[u];                                           \
      float kv = kb1 ? P2[u] : P0[u];                                           \
      q[u] = kv + dppf<DPP_XOR2>(gv);                                           \
    }                                                                           \
    _Pragma("unroll")                                                           \
    for (int u = 0; u < 4; ++u) q[u] += dppf<DPP_ROR4>(q[u]);                   \
    _Pragma("unroll")                                                           \
    for (int u = 0; u < 4; ++u) q[u] += dppf<DPP_ROR8>(q[u]);                   \
    _Pragma("unroll")                                                           \
    for (int u = 0; u < 4; ++u) q[u] += swz16f(q[u]);                           \
    float exc[4];                                                               \
    _Pragma("unroll")                                                           \
    for (int u = 0; u < 4; ++u) {                                               \
      float sdot = fmaf(s0[u], cw0, fmaf(s1[u], cw1, s2[u] * cw2));             \
      exc[u] = __expf(fmaf(onema, sdot + q[u], cbase));                         \
    }                                                                           \
    float vq[4];                                                                \
    _Pragma("unroll")                                                           \
    for (int u = 0; u < 4; ++u) {                                               \
      float z, h, acc;                                                          \
      z = fmaf(s0[u], w1a.x, fmaf(s1[u], w1b.x, fmaf(s2[u], w1c.x, b1v.x))); h = fast_gelu(z); acc = h * w2v.x; \
      z = fmaf(s0[u], w1a.y, fmaf(s1[u], w1b.y, fmaf(s2[u], w1c.y, b1v.y))); h = fast_gelu(z); acc = fmaf(h, w2v.y, acc); \
      z = fmaf(s0[u], w1a.z, fmaf(s1[u], w1b.z, fmaf(s2[u], w1c.z, b1v.z))); h = fast_gelu(z); acc = fmaf(h, w2v.z, acc); \
      z = fmaf(s0[u], w1a.w, fmaf(s1[u], w1b.w, fmaf(s2[u], w1c.w, b1v.w))); h = fast_gelu(z); acc = fmaf(h, w2v.w, acc); \
      vq[u] = exc[u] * (acc + b2o8);                                            \
    }                                                                           \
    _Pragma("unroll")                                                           \
    for (int u = 0; u < 4; ++u) vq[u] += dppf<DPP_ROR4>(vq[u]);                 \
    _Pragma("unroll")                                                           \
    for (int u = 0; u < 4; ++u) vq[u] += dppf<DPP_ROR8>(vq[u]);                 \
    _Pragma("unroll")                                                           \
    for (int u = 0; u < 4; ++u) vq[u] += swz16f(vq[u]);                         \
    if (r < 8) {                                                                \
      _Pragma("unroll")                                                         \
      for (int u = 0; u < 4; ++u) {                                             \
        const int el = e0 + u * 16;                                             \
        elds[el * 8 + r] = (r < 4) ? vq[u] : exc[u];                            \
      }                                                                         \
    }                                                                           \
    /* cust accumulate: tree into single accumulator (saves 12 VGPR) */         \
    a0.x += (v0.x + v1.x) + (v2.x + v3.x);                                      \
    a0.y += (v0.y + v1.y) + (v2.y + v3.y);                                      \
    a0.z += (v0.z + v1.z) + (v2.z + v3.z);                                      \
    a0.w += (v0.w + v1.w) + (v2.w + v3.w);                                      \
  }

__global__ __launch_bounds__(512, 4) void k_all(
    const float* __restrict__ scores, const float* __restrict__ veh,
    const float* __restrict__ cust, const float* __restrict__ edge,
    const float* __restrict__ ew1, const float* __restrict__ eb1,
    const float* __restrict__ ew2, const float* __restrict__ eb2,
    const float* __restrict__ sw1, const float* __restrict__ sb1,
    const float* __restrict__ sw2, const float* __restrict__ sb2,
    const float* __restrict__ cand_w, const float* __restrict__ cand_b,
    const float* __restrict__ edge_w, const float* __restrict__ gbp,
    float* __restrict__ out)
{
    // shbuf aliases: scores (float4[768], main loop) THEN reduce buf
    // (float4[512], after main loop). Disjoint live ranges, barrier between.
    __shared__ float shbuf[3072];          // 12 KB
    __shared__ float sin_[2 * DD];
    __shared__ float hg[GG];
    __shared__ float slds[KK];
    __shared__ float elds[LL * 8];         // 32 KB: per-element {V0..3,E0..3}

    const int n = blockIdx.x;
    const int t = threadIdx.x;
    const int r = t & 31;                  // lane-in-32  (== cust column)
    const int base_el = t >> 5;            // 0..15       (== cust row slice)

    const int ko = r & 3;        // owned gate/expert channel
    const int jg = r >> 2;       // owned hidden quad (0..7)
    const bool kb0 = (r & 1) != 0;
    const bool kb1 = (r & 2) != 0;

    // ---- stage scores -> LDS (coalesced float4) ----
    {
        const float4* sp4 = (const float4*)(scores + (size_t)n * LL * SS);
        float4* sc4 = (float4*)shbuf;
        sc4[t] = sp4[t];
        if (t < 256) sc4[512 + t] = sp4[512 + t];
    }

    // per-lane constant weights (latency hidden behind staging)
    const float4* ew4 = (const float4*)edge_w;            // (D,K)
    const float4 wqa = ew4[4 * r + 0];
    const float4 wqb = ew4[4 * r + 1];
    const float4 wqc = ew4[4 * r + 2];
    const float4 wqd = ew4[4 * r + 3];
    const float cw0 = cand_w[0 * KK + ko];
    const float cw1 = cand_w[1 * KK + ko];
    const float cw2 = cand_w[2 * KK + ko];
    const float4* w1f = (const float4*)ew1;               // (K,S,H)
    const float4 w1a = w1f[(ko * SS + 0) * (HH / 4) + jg];
    const float4 w1b = w1f[(ko * SS + 1) * (HH / 4) + jg];
    const float4 w1c = w1f[(ko * SS + 2) * (HH / 4) + jg];
    const float4 b1v = ((const float4*)eb1)[ko * (HH / 4) + jg];
    const float4 w2v = ((const float4*)ew2)[ko * (HH / 4) + jg];
    const float b2o8 = 0.125f * eb2[ko];   // b2 folded into per-lane partial
    const float alpha = 1.0f / (1.0f + __expf(-gbp[0]));
    const float onema = 1.0f - alpha;
    const float cbase = onema * cand_b[ko];  // (1-a)*cand_b folded into exc

    __syncthreads();   // scores staged

    const float* sc_lds = shbuf;
    const float4* cp = (const float4*)(cust + (size_t)n * LL * DD);
    const float* ed_base = edge + (size_t)n * LL * DD;

    // ---- pipelined fused main loop ----
    float4 ev_a[4], ev_b[4];
    #pragma unroll
    for (int u = 0; u < 4; ++u)
        ev_a[u] = *(const float4*)(ed_base + (size_t)(base_el + u * 16) * DD + r * 4);

    float4 a0 = make_float4(0.f, 0.f, 0.f, 0.f);

    for (int ii = 0; ii < 14; ii += 2) {
        BODY(ii,     ev_a, ev_b, 1)
        BODY(ii + 1, ev_b, ev_a, 1)
    }
    BODY(14, ev_a, ev_b, 1)
    BODY(15, ev_b, ev_a, 0)

    // ---- cust mean reduce (shbuf now re-used as reduce buffer) ----
    __syncthreads();                        // all sc_lds reads done
    float4* redv = (float4*)shbuf;
    redv[t] = a0;
    __syncthreads();

    if (t < 32) {
        float4 s = redv[t];
        #pragma unroll
        for (int i = 1; i < 16; i++) {
            float4 v = redv[i * 32 + t];
            s.x += v.x; s.y += v.y; s.z += v.z; s.w += v.w;
        }
        const float inv = 1.0f / (float)LL;
        sin_[DD + 4 * t + 0] = s.x * inv;
        sin_[DD + 4 * t + 1] = s.y * inv;
        sin_[DD + 4 * t + 2] = s.z * inv;
        sin_[DD + 4 * t + 3] = s.w * inv;
        float4 vv = ((const float4*)(veh + (size_t)n * DD))[t];
        sin_[4 * t + 0] = vv.x; sin_[4 * t + 1] = vv.y;
        sin_[4 * t + 2] = vv.z; sin_[4 * t + 3] = vv.w;
    }
    __syncthreads();

    // ---- situation MLP (4-way split: chain depth 64) ----
    float* redf = shbuf;
    if (t < 256) {
        const int g = t & 63;
        const int part = t >> 6;
        float a = 0.f;
        #pragma unroll 8
        for (int i = 0; i < 64; ++i) {
            const int row = part * 64 + i;
            a = fmaf(sin_[row], sw1[row * GG + g], a);
        }
        redf[t] = a;
    }
    __syncthreads();
    if (t < GG) {
        float a = sb1[t] + redf[t] + redf[t + 64] + redf[t + 128] + redf[t + 192];
        hg[t] = fast_gelu(a);
    }
    __syncthreads();
    if (t < KK) {
        float a = sb2[t];
        #pragma unroll
        for (int g = 0; g < GG; g++)
            a = fmaf(hg[g], sw2[g * KK + t], a);
        slds[t] = a;
    }
    __syncthreads();

    // ---- final normalize: out = sum_k m_k V_k / sum_k m_k E_k ----
    const float m0 = __expf(alpha * slds[0]);
    const float m1 = __expf(alpha * slds[1]);
    const float m2 = __expf(alpha * slds[2]);
    const float m3 = __expf(alpha * slds[3]);
    float* out_base = out + (size_t)n * LL;
    #pragma unroll
    for (int e = t; e < LL; e += 512) {
        const float4 V = *(const float4*)&elds[e * 8];
        const float4 E = *(const float4*)&elds[e * 8 + 4];
        float num = fmaf(m0, V.x, fmaf(m1, V.y, fmaf(m2, V.z, m3 * V.w)));
        float den = fmaf(m0, E.x, fmaf(m1, E.y, fmaf(m2, E.z, m3 * E.w)));
        out_base[e] = num * __builtin_amdgcn_rcpf(den);
    }
}

extern "C" void kernel_launch(void* const* d_in, const int* in_sizes, int n_in,
                              void* d_out, int out_size, void* d_ws, size_t ws_size,
                              hipStream_t stream)
{
    const float* scores = (const float*)d_in[0];
    const float* veh    = (const float*)d_in[1];
    const float* cust   = (const float*)d_in[2];
    const float* edge   = (const float*)d_in[3];
    const float* ew1    = (const float*)d_in[4];
    const float* eb1    = (const float*)d_in[5];
    const float* ew2    = (const float*)d_in[6];
    const float* eb2    = (const float*)d_in[7];
    const float* sw1    = (const float*)d_in[8];
    const float* sb1    = (const float*)d_in[9];
    const float* sw2    = (const float*)d_in[10];
    const float* sb2    = (const float*)d_in[11];
    const float* cw     = (const float*)d_in[12];
    const float* cb     = (const float*)d_in[13];
    const float* egw    = (const float*)d_in[14];
    const float* gb     = (const float*)d_in[15];
    float* out = (float*)d_out;

    hipLaunchKernelGGL(k_all, dim3(NN), dim3(512), 0, stream,
                       scores, veh, cust, edge, ew1, eb1, ew2, eb2,
                       sw1, sb1, sw2, sb2, cw, cb, egw, gb, out);
}

// Round 4
// 548.386 us; speedup vs baseline: 1.0200x; 1.0200x over previous
//
#include <hip/hip_runtime.h>

// Problem dims (fixed by harness)
#define NN 512
#define LL 1024
#define SS 3
#define DD 128
#define KK 4
#define HH 32
#define GG 64

// DPP ctrl encodings (gfx9/CDNA): cross-lane moves on the VALU pipe.
#define DPP_XOR1 0xB1   // quad_perm [1,0,3,2]  == lane ^ 1
#define DPP_XOR2 0x4E   // quad_perm [2,3,0,1]  == lane ^ 2
#define DPP_ROR4 0x124  // row_ror:4
#define DPP_ROR8 0x128  // row_ror:8
#define SWZ16 0x401F    // ds_swizzle BitMode xor-16 within 32-lane group

template <int CTRL>
__device__ __forceinline__ float dppf(float x) {
    return __int_as_float(__builtin_amdgcn_update_dpp(
        0, __float_as_int(x), CTRL, 0xF, 0xF, true));
}
__device__ __forceinline__ float swz16f(float x) {
    return __int_as_float(__builtin_amdgcn_ds_swizzle(__float_as_int(x), SWZ16));
}

// tanh-form GELU: max |err| vs exact erf-GELU ~3e-4 -- far under threshold.
__device__ __forceinline__ float fast_gelu(float x) {
    const float c0 = 0.7978845608028654f;
    const float c1 = 0.7978845608028654f * 0.044715f;
    float u = x * x;
    float y = x * fmaf(c1, u, c0);
    float e = __expf(2.0f * y);
    float r = __builtin_amdgcn_rcpf(e + 1.0f);
    float t = fmaf(-2.0f, r, 1.0f);
    return 0.5f * x * (1.0f + t);
}

// ---------------- kernel 1: cust mean + situation MLP ----------------
// One block per n. Streams cust[n] (256 KB), computes mean, sit MLP,
// writes ws[n*4+k] = alpha * sit_logit_k  (log-space; folded into the
// per-element exp in k_elem). Pure-BW kernel.
__global__ __launch_bounds__(512) void k_sit(
    const float* __restrict__ veh, const float* __restrict__ cust,
    const float* __restrict__ sw1, const float* __restrict__ sb1,
    const float* __restrict__ sw2, const float* __restrict__ sb2,
    const float* __restrict__ gbp, float* __restrict__ ws)
{
    __shared__ float4 red[512];
    __shared__ float sin_[2 * DD];
    __shared__ float hg[GG];

    const int n = blockIdx.x;
    const int t = threadIdx.x;
    const int c = t & 31;
    const int rs = t >> 5;

    const float4* cp = (const float4*)(cust + (size_t)n * LL * DD);
    float4 a0 = make_float4(0.f, 0.f, 0.f, 0.f), a1 = a0, a2 = a0, a3 = a0;
    #pragma unroll 4
    for (int i = 0; i < 16; ++i) {
        float4 v0 = cp[(rs + 16 * i      ) * 32 + c];
        float4 v1 = cp[(rs + 16 * i + 256) * 32 + c];
        float4 v2 = cp[(rs + 16 * i + 512) * 32 + c];
        float4 v3 = cp[(rs + 16 * i + 768) * 32 + c];
        a0.x += v0.x; a0.y += v0.y; a0.z += v0.z; a0.w += v0.w;
        a1.x += v1.x; a1.y += v1.y; a1.z += v1.z; a1.w += v1.w;
        a2.x += v2.x; a2.y += v2.y; a2.z += v2.z; a2.w += v2.w;
        a3.x += v3.x; a3.y += v3.y; a3.z += v3.z; a3.w += v3.w;
    }
    a0.x += a1.x + a2.x + a3.x;
    a0.y += a1.y + a2.y + a3.y;
    a0.z += a1.z + a2.z + a3.z;
    a0.w += a1.w + a2.w + a3.w;
    red[t] = a0;
    __syncthreads();

    if (t < 32) {
        float4 s = red[t];
        #pragma unroll
        for (int i = 1; i < 16; i++) {
            float4 v = red[i * 32 + t];
            s.x += v.x; s.y += v.y; s.z += v.z; s.w += v.w;
        }
        const float inv = 1.0f / (float)LL;
        sin_[DD + 4 * t + 0] = s.x * inv;
        sin_[DD + 4 * t + 1] = s.y * inv;
        sin_[DD + 4 * t + 2] = s.z * inv;
        sin_[DD + 4 * t + 3] = s.w * inv;
        float4 vv = ((const float4*)(veh + (size_t)n * DD))[t];
        sin_[4 * t + 0] = vv.x; sin_[4 * t + 1] = vv.y;
        sin_[4 * t + 2] = vv.z; sin_[4 * t + 3] = vv.w;
    }
    __syncthreads();

    // situation MLP layer 1 (4-way split: chain depth 64)
    float* redf = (float*)red;
    if (t < 256) {
        const int g = t & 63;
        const int part = t >> 6;
        float a = 0.f;
        #pragma unroll 8
        for (int i = 0; i < 64; ++i) {
            const int row = part * 64 + i;
            a = fmaf(sin_[row], sw1[row * GG + g], a);
        }
        redf[t] = a;
    }
    __syncthreads();
    if (t < GG) {
        float a = sb1[t] + redf[t] + redf[t + 64] + redf[t + 128] + redf[t + 192];
        hg[t] = fast_gelu(a);
    }
    __syncthreads();
    if (t < KK) {
        float a = sb2[t];
        #pragma unroll
        for (int g = 0; g < GG; g++)
            a = fmaf(hg[g], sw2[g * KK + t], a);
        const float alpha = 1.0f / (1.0f + __expf(-gbp[0]));
        ws[n * KK + t] = alpha * a;   // log-space; consumed by k_elem
    }
}

// ---------------- kernel 2: per-element gate + expert + normalize ----------
// 4096 blocks x 256 threads: block b handles n = b>>3, elements
// [128*(b&7), +128). 32 lanes per element, 8 elements per iter, 16 iters.
// Tiny LDS (1.5 KB) + modest VGPR -> 6 waves/SIMD: latency hiding via TLP.
// Factorized softmax: exp(a*sit + (1-a)*cand) = exp((1-a)*cand + a*sit),
// a*sit comes from ws in log space -> out computed in one pass, no parking.
__global__ __launch_bounds__(256, 6) void k_elem(
    const float* __restrict__ scores, const float* __restrict__ edge,
    const float* __restrict__ ew1, const float* __restrict__ eb1,
    const float* __restrict__ ew2, const float* __restrict__ eb2,
    const float* __restrict__ cand_w, const float* __restrict__ cand_b,
    const float* __restrict__ edge_w, const float* __restrict__ gbp,
    const float* __restrict__ ws, float* __restrict__ out)
{
    __shared__ float4 sc4[96];   // this block's 128 elements x 3 scores

    const int b = blockIdx.x;
    const int n = b >> 3;
    const int chunk = b & 7;
    const int t = threadIdx.x;
    const int r = t & 31;
    const int g = t >> 5;        // element group 0..7

    // stage this chunk's scores (384 floats)
    {
        const float4* sp4 = (const float4*)(scores + (size_t)n * LL * SS) + 96 * chunk;
        if (t < 96) sc4[t] = sp4[t];
    }

    const int ko = r & 3;        // owned gate/expert channel
    const int jg = r >> 2;       // owned hidden quad (0..7)
    const bool kb0 = (r & 1) != 0;
    const bool kb1 = (r & 2) != 0;

    // per-lane constants (hidden under staging)
    const float4* ew4 = (const float4*)edge_w;            // (D,K)
    const float4 wqa = ew4[4 * r + 0];
    const float4 wqb = ew4[4 * r + 1];
    const float4 wqc = ew4[4 * r + 2];
    const float4 wqd = ew4[4 * r + 3];
    const float cw0 = cand_w[0 * KK + ko];
    const float cw1 = cand_w[1 * KK + ko];
    const float cw2 = cand_w[2 * KK + ko];
    const float4* w1f = (const float4*)ew1;               // (K,S,H)
    const float4 w1a = w1f[(ko * SS + 0) * (HH / 4) + jg];
    const float4 w1b = w1f[(ko * SS + 1) * (HH / 4) + jg];
    const float4 w1c = w1f[(ko * SS + 2) * (HH / 4) + jg];
    const float4 b1v = ((const float4*)eb1)[ko * (HH / 4) + jg];
    const float4 w2v = ((const float4*)ew2)[ko * (HH / 4) + jg];
    const float b2o8 = 0.125f * eb2[ko];
    const float alpha = 1.0f / (1.0f + __expf(-gbp[0]));
    const float onema = 1.0f - alpha;
    // exp bias: (1-a)*cand_b[k] + a*sit_logit[k]  (log-space fold of m_k)
    const float eb_ = fmaf(onema, cand_b[ko], ws[n * KK + ko]);

    __syncthreads();

    const float* sc_lds = (const float*)sc4;
    const float* ed_base = edge + (size_t)n * LL * DD + (size_t)(chunk * 128) * DD;
    float* outp = out + (size_t)n * LL + chunk * 128;

    float4 ev = *(const float4*)(ed_base + (size_t)g * DD + r * 4);

    for (int i = 0; i < 16; ++i) {
        const int le = i * 8 + g;                 // local element 0..127
        const int ln = (i < 15) ? le + 8 : le;    // next (redundant on last: L1 hit)
        float4 evn = *(const float4*)(ed_base + (size_t)ln * DD + r * 4);

        const float s0 = sc_lds[le * 3 + 0];      // uniform in group -> broadcast
        const float s1 = sc_lds[le * 3 + 1];
        const float s2 = sc_lds[le * 3 + 2];

        // edge-dot partials for all 4 k over the lane's 4 dims
        float p0 = fmaf(ev.x, wqa.x, fmaf(ev.y, wqb.x, fmaf(ev.z, wqc.x, ev.w * wqd.x)));
        float p1 = fmaf(ev.x, wqa.y, fmaf(ev.y, wqb.y, fmaf(ev.z, wqc.y, ev.w * wqd.y)));
        float p2 = fmaf(ev.x, wqa.z, fmaf(ev.y, wqb.z, fmaf(ev.z, wqc.z, ev.w * wqd.z)));
        float p3 = fmaf(ev.x, wqa.w, fmaf(ev.y, wqb.w, fmaf(ev.z, wqc.w, ev.w * wqd.w)));

        // k-preserving butterfly: xor1, xor2, then jg-sum (ror4+ror8+xor16)
        float g0 = kb0 ? p0 : p1, k0 = kb0 ? p1 : p0;
        float g2 = kb0 ? p2 : p3, k2 = kb0 ? p3 : p2;
        float P0 = k0 + dppf<DPP_XOR1>(g0);
        float P2 = k2 + dppf<DPP_XOR1>(g2);
        float gv = kb1 ? P0 : P2, kv = kb1 ? P2 : P0;
        float q = kv + dppf<DPP_XOR2>(gv);
        q += dppf<DPP_ROR4>(q);
        q += dppf<DPP_ROR8>(q);
        q += swz16f(q);
        // q = edge_dot[k=ko], replicated over the 8 jg lanes

        // gate exp with sit logit folded in log-space (single exp)
        const float sdot = fmaf(s0, cw0, fmaf(s1, cw1, s2 * cw2));
        const float excm = __expf(fmaf(onema, sdot + q, eb_));

        // expert MLP: 4 hidden units of own k
        float z, h, acc;
        z = fmaf(s0, w1a.x, fmaf(s1, w1b.x, fmaf(s2, w1c.x, b1v.x))); h = fast_gelu(z); acc = h * w2v.x;
        z = fmaf(s0, w1a.y, fmaf(s1, w1b.y, fmaf(s2, w1c.y, b1v.y))); h = fast_gelu(z); acc = fmaf(h, w2v.y, acc);
        z = fmaf(s0, w1a.z, fmaf(s1, w1b.z, fmaf(s2, w1c.z, b1v.z))); h = fast_gelu(z); acc = fmaf(h, w2v.z, acc);
        z = fmaf(s0, w1a.w, fmaf(s1, w1b.w, fmaf(s2, w1c.w, b1v.w))); h = fast_gelu(z); acc = fmaf(h, w2v.w, acc);
        float vq = excm * (acc + b2o8);

        // paired full 32-lane sums: num (vq) and den (excm), independent chains
        float de = excm;
        vq += dppf<DPP_XOR1>(vq);  de += dppf<DPP_XOR1>(de);
        vq += dppf<DPP_XOR2>(vq);  de += dppf<DPP_XOR2>(de);
        vq += dppf<DPP_ROR4>(vq);  de += dppf<DPP_ROR4>(de);
        vq += dppf<DPP_ROR8>(vq);  de += dppf<DPP_ROR8>(de);
        vq += swz16f(vq);          de += swz16f(de);
        // de = 8 * sum_k m_k exc_k (each k counted 8x); vq = true numerator

        if (r == 0) outp[le] = 8.0f * vq * __builtin_amdgcn_rcpf(de);

        ev = evn;
    }
}

extern "C" void kernel_launch(void* const* d_in, const int* in_sizes, int n_in,
                              void* d_out, int out_size, void* d_ws, size_t ws_size,
                              hipStream_t stream)
{
    const float* scores = (const float*)d_in[0];
    const float* veh    = (const float*)d_in[1];
    const float* cust   = (const float*)d_in[2];
    const float* edge   = (const float*)d_in[3];
    const float* ew1    = (const float*)d_in[4];
    const float* eb1    = (const float*)d_in[5];
    const float* ew2    = (const float*)d_in[6];
    const float* eb2    = (const float*)d_in[7];
    const float* sw1    = (const float*)d_in[8];
    const float* sb1    = (const float*)d_in[9];
    const float* sw2    = (const float*)d_in[10];
    const float* sb2    = (const float*)d_in[11];
    const float* cw     = (const float*)d_in[12];
    const float* cb     = (const float*)d_in[13];
    const float* egw    = (const float*)d_in[14];
    const float* gb     = (const float*)d_in[15];
    float* out = (float*)d_out;
    float* ws  = (float*)d_ws;   // 512*4 floats = 8 KB

    hipLaunchKernelGGL(k_sit, dim3(NN), dim3(512), 0, stream,
                       veh, cust, sw1, sb1, sw2, sb2, gb, ws);
    hipLaunchKernelGGL(k_elem, dim3(NN * 8), dim3(256), 0, stream,
                       scores, edge, ew1, eb1, ew2, eb2,
                       cw, cb, egw, gb, ws, out);
}